// Round 4
// baseline (398.897 us; speedup 1.0000x reference)
//
#include <hip/hip_runtime.h>

#define NB 8
#define NL 2048
#define ND 128
#define NH 128
#define MASKVAL (-1e30f)

typedef __attribute__((ext_vector_type(8))) short short8;
typedef __attribute__((ext_vector_type(4))) float f32x4;

__device__ __forceinline__ unsigned short bf16_rn(float f) {
  unsigned u = __float_as_uint(f);
  u += 0x7fffu + ((u >> 16) & 1u);
  return (unsigned short)(u >> 16);
}
__device__ __forceinline__ float bf16_tof(unsigned short h) {
  return __uint_as_float(((unsigned)h) << 16);
}

// ---------- Kernel 0: W transpose + hi/lo split into bf16 planes ----------
// Wth[h][d] = bf16(W[d][h]); Wtl[h][d] = bf16(residual)
__global__ __launch_bounds__(256) void wprep_kernel(
    const float* __restrict__ Wq, const float* __restrict__ Wk,
    short* __restrict__ wthq, short* __restrict__ wtlq,
    short* __restrict__ wthk, short* __restrict__ wtlk)
{
  int m = blockIdx.x >> 4;            // 0 = q, 1 = k
  int bb = blockIdx.x & 15;
  const float* W = m ? Wk : Wq;
  short* wth = m ? wthk : wthq;
  short* wtl = m ? wtlk : wtlq;
  int idx = bb * 256 + threadIdx.x;   // 0..4095
  int d = idx >> 5, hc = idx & 31;
  float4 wv = *(const float4*)(W + d * NH + hc * 4);
  float vv[4] = {wv.x, wv.y, wv.z, wv.w};
#pragma unroll
  for (int j = 0; j < 4; ++j) {
    int h = hc * 4 + j;
    unsigned short hb = bf16_rn(vv[j]);
    unsigned short lb = bf16_rn(vv[j] - bf16_tof(hb));
    wth[h * ND + d] = (short)hb;
    wtl[h * ND + d] = (short)lb;
  }
}

// ---------- Kernel 1: V transpose to bf16, vt[b][d][key] ------------------
// LDS-tiled 64x64 transpose; 4B paired stores (2-way banks), vectorized out.
__global__ __launch_bounds__(256) void vtprep_kernel(
    const float* __restrict__ value, short* __restrict__ vt)
{
  __shared__ short Tl[64][66];
  int b = blockIdx.x >> 6;
  int k0 = ((blockIdx.x >> 1) & 31) * 64;
  int d0 = (blockIdx.x & 1) * 64;
  int t = threadIdx.x;
  int dm = t & 7, kp = t >> 3;        // dm: 8 d-chunks of 8; kp: 32 key pairs
  float v0[8], v1[8];
  {
    const float* vp0 = value + (size_t)(b * NL + k0 + kp * 2) * ND + d0 + dm * 8;
    const float* vp1 = vp0 + ND;
    float4 a0 = *(const float4*)vp0;       float4 c0 = *(const float4*)(vp0 + 4);
    float4 a1 = *(const float4*)vp1;       float4 c1 = *(const float4*)(vp1 + 4);
    v0[0]=a0.x; v0[1]=a0.y; v0[2]=a0.z; v0[3]=a0.w; v0[4]=c0.x; v0[5]=c0.y; v0[6]=c0.z; v0[7]=c0.w;
    v1[0]=a1.x; v1[1]=a1.y; v1[2]=a1.z; v1[3]=a1.w; v1[4]=c1.x; v1[5]=c1.y; v1[6]=c1.z; v1[7]=c1.w;
  }
#pragma unroll
  for (int j = 0; j < 8; ++j) {
    unsigned pk = (unsigned)bf16_rn(v0[j]) | ((unsigned)bf16_rn(v1[j]) << 16);
    *(unsigned*)&Tl[dm * 8 + j][kp * 2] = pk;
  }
  __syncthreads();
  int dr = t >> 2, kc = t & 3;        // dr 0..63, kc: 4 chunks of 16 keys
  const unsigned* base = (const unsigned*)&Tl[dr][0];
  unsigned w[8];
#pragma unroll
  for (int i = 0; i < 8; ++i) w[i] = base[kc * 8 + i];
  short* op = vt + (size_t)(b * ND + d0 + dr) * NL + k0 + kc * 16;
  *(uint4*)op = make_uint4(w[0], w[1], w[2], w[3]);
  *(uint4*)(op + 8) = make_uint4(w[4], w[5], w[6], w[7]);
}

// ---------- Kernel 2: projection (split-bf16 MFMA, W from planes) ---------
// y==0: q -> qhl packed u32. y==1: k -> khp/klp bf16 planes.
__global__ __launch_bounds__(256) void proj_kernel(
    const float* __restrict__ query, const float* __restrict__ key,
    const short* __restrict__ wthq, const short* __restrict__ wtlq,
    const short* __restrict__ wthk, const short* __restrict__ wtlk,
    unsigned* __restrict__ qhl, short* __restrict__ khp, short* __restrict__ klp)
{
  const float* X = blockIdx.y ? key : query;
  const short* wth = blockIdx.y ? wthk : wthq;
  const short* wtl = blockIdx.y ? wtlk : wtlq;

  int tid = threadIdx.x;
  int wave = tid >> 6, lane = tid & 63;
  int lr = lane & 15, dg = lane >> 4;
  int arow = blockIdx.x * 64 + wave * 16 + lr;

  short8 ah[4], al[4];
  const float* xr = X + (size_t)arow * ND;
#pragma unroll
  for (int ks = 0; ks < 4; ++ks) {
    float4 a0 = *(const float4*)(xr + ks * 32 + dg * 8);
    float4 a1 = *(const float4*)(xr + ks * 32 + dg * 8 + 4);
    float vv[8] = {a0.x, a0.y, a0.z, a0.w, a1.x, a1.y, a1.z, a1.w};
    short8 h, l;
#pragma unroll
    for (int j = 0; j < 8; ++j) {
      unsigned short hb = bf16_rn(vv[j]);
      h[j] = (short)hb;
      l[j] = (short)bf16_rn(vv[j] - bf16_tof(hb));
    }
    ah[ks] = h; al[ks] = l;
  }

#pragma unroll
  for (int cf = 0; cf < 8; ++cf) {
    f32x4 acc = {0.f, 0.f, 0.f, 0.f};
    int col = cf * 16 + lr;
    const short* whp = wth + (size_t)col * ND;
    const short* wlp = wtl + (size_t)col * ND;
#pragma unroll
    for (int ks = 0; ks < 4; ++ks) {
      short8 wh = *(const short8*)(whp + ks * 32 + dg * 8);
      short8 wl = *(const short8*)(wlp + ks * 32 + dg * 8);
      acc = __builtin_amdgcn_mfma_f32_16x16x32_bf16(ah[ks], wh, acc, 0, 0, 0);
      acc = __builtin_amdgcn_mfma_f32_16x16x32_bf16(al[ks], wh, acc, 0, 0, 0);
      acc = __builtin_amdgcn_mfma_f32_16x16x32_bf16(ah[ks], wl, acc, 0, 0, 0);
    }
#pragma unroll
    for (int r = 0; r < 4; ++r) {
      int orow = blockIdx.x * 64 + wave * 16 + dg * 4 + r;
      float v = acc[r];
      unsigned short hb = bf16_rn(v);
      unsigned short lb = bf16_rn(v - bf16_tof(hb));
      if (blockIdx.y == 0) {
        qhl[(size_t)orow * NH + col] = ((unsigned)lb << 16) | (unsigned)hb;
      } else {
        khp[(size_t)orow * NH + col] = (short)hb;
        klp[(size_t)orow * NH + col] = (short)lb;
      }
    }
  }
}

// ---------- staging helpers for attn --------------------------------------
__device__ __forceinline__ void stage_load(uint4* rg,
    const short* __restrict__ khp, const short* __restrict__ klp,
    const short* __restrict__ vt, int b, int kt, int su)
{
#pragma unroll
  for (int c = 0; c < 4; ++c) {
    int idx = c * 128 + su;
    int row = idx >> 4, ch = idx & 15;
    size_t gk = (size_t)(b * NL + kt * 32 + row) * NH + ch * 8;
    rg[c]     = *(const uint4*)(khp + gk);
    rg[4 + c] = *(const uint4*)(klp + gk);
  }
#pragma unroll
  for (int c = 0; c < 4; ++c) {
    int idx = c * 128 + su;
    int d = idx >> 2, kc = idx & 3;
    rg[8 + c] = *(const uint4*)(vt + (size_t)(b * ND + d) * NL + kt * 32 + kc * 8);
  }
}

// ---------- Kernel 3: fused flash attention --------------------------------
__global__ __launch_bounds__(256, 3) void attn_kernel(
    const unsigned* __restrict__ qhl, const short* __restrict__ khp,
    const short* __restrict__ klp, const short* __restrict__ vt,
    const float* __restrict__ mask, float* __restrict__ out)
{
  __shared__ short KH[2][32][128];
  __shared__ short KL[2][32][128];
  __shared__ short VT[2][128][32];
  __shared__ short Plds[4][16][40];

  int tid = threadIdx.x;
  int wave = tid >> 6, lane = tid & 63;
  int lr = lane & 15, dg = lane >> 4;
  int b = blockIdx.x & 7, qt = blockIdx.x >> 3;   // XCD swizzle: batch -> XCD
  int wr = wave & 1, wk = wave >> 1;
  int q0 = qt * 32;

  // Q fragments (packed hi|lo u32 -> split)
  short8 qh[4], ql[4];
  {
    const unsigned* qp = qhl + (size_t)(b * NL + q0 + wr * 16 + lr) * NH;
#pragma unroll
    for (int ks = 0; ks < 4; ++ks) {
      uint4 u0 = *(const uint4*)(qp + ks * 32 + dg * 8);
      uint4 u1 = *(const uint4*)(qp + ks * 32 + dg * 8 + 4);
      unsigned uv[8] = {u0.x, u0.y, u0.z, u0.w, u1.x, u1.y, u1.z, u1.w};
      short8 h, l;
#pragma unroll
      for (int j = 0; j < 8; ++j) {
        h[j] = (short)(uv[j] & 0xffffu);
        l[j] = (short)(uv[j] >> 16);
      }
      qh[ks] = h; ql[ks] = l;
    }
  }

  f32x4 accv[8];
#pragma unroll
  for (int f = 0; f < 8; ++f) accv[f] = (f32x4){0.f, 0.f, 0.f, 0.f};
  float mrow[4] = {-__builtin_inff(), -__builtin_inff(), -__builtin_inff(), -__builtin_inff()};
  float lrow[4] = {0.f, 0.f, 0.f, 0.f};

  int su = tid & 127, ss = tid >> 7;
  uint4 rg[12];
  stage_load(rg, khp, klp, vt, b, 0 * 2 + ss, su);

  const int NPAIR = NL / 64;   // 32
  for (int p = 0; p < NPAIR; ++p) {
    __syncthreads();           // previous compute finished reading LDS
    // regs -> LDS (linear, conflict-free)
#pragma unroll
    for (int c = 0; c < 4; ++c) {
      int idx = c * 128 + su;
      int row = idx >> 4, ch = idx & 15;
      *(uint4*)&KH[ss][row][ch * 8] = rg[c];
      *(uint4*)&KL[ss][row][ch * 8] = rg[4 + c];
    }
#pragma unroll
    for (int c = 0; c < 4; ++c) {
      int idx = c * 128 + su;
      int d = idx >> 2, kc = idx & 3;
      *(uint4*)&VT[ss][d][kc * 8] = rg[8 + c];
    }
    __syncthreads();
    if (p + 1 < NPAIR) stage_load(rg, khp, klp, vt, b, (p + 1) * 2 + ss, su);

    // ---- compute this wave's tile: kt = p*2 + wk, slot wk
    int kt = p * 2 + wk;
    const int s = wk;
    f32x4 sc0 = {0.f, 0.f, 0.f, 0.f}, sc1 = {0.f, 0.f, 0.f, 0.f};
#pragma unroll
    for (int ks = 0; ks < 4; ++ks) {
      short8 b0h = *(const short8*)&KH[s][lr][ks * 32 + dg * 8];
      short8 b0l = *(const short8*)&KL[s][lr][ks * 32 + dg * 8];
      short8 b1h = *(const short8*)&KH[s][16 + lr][ks * 32 + dg * 8];
      short8 b1l = *(const short8*)&KL[s][16 + lr][ks * 32 + dg * 8];
      sc0 = __builtin_amdgcn_mfma_f32_16x16x32_bf16(qh[ks], b0h, sc0, 0, 0, 0);
      sc1 = __builtin_amdgcn_mfma_f32_16x16x32_bf16(qh[ks], b1h, sc1, 0, 0, 0);
      sc0 = __builtin_amdgcn_mfma_f32_16x16x32_bf16(ql[ks], b0h, sc0, 0, 0, 0);
      sc1 = __builtin_amdgcn_mfma_f32_16x16x32_bf16(ql[ks], b1h, sc1, 0, 0, 0);
      sc0 = __builtin_amdgcn_mfma_f32_16x16x32_bf16(qh[ks], b0l, sc0, 0, 0, 0);
      sc1 = __builtin_amdgcn_mfma_f32_16x16x32_bf16(qh[ks], b1l, sc1, 0, 0, 0);
    }
    float mk0 = mask[b * NL + kt * 32 + lr];
    float mk1 = mask[b * NL + kt * 32 + 16 + lr];
    float pr0[4], pr1[4];
#pragma unroll
    for (int r = 0; r < 4; ++r) {
      float s0 = mk0 * sc0[r] + (1.f - mk0) * MASKVAL;
      float s1 = mk1 * sc1[r] + (1.f - mk1) * MASKVAL;
      float vmax = fmaxf(s0, s1);
      vmax = fmaxf(vmax, __shfl_xor(vmax, 1));
      vmax = fmaxf(vmax, __shfl_xor(vmax, 2));
      vmax = fmaxf(vmax, __shfl_xor(vmax, 4));
      vmax = fmaxf(vmax, __shfl_xor(vmax, 8));
      float mn = fmaxf(mrow[r], vmax);
      float alpha = __expf(mrow[r] - mn);
      float p0 = __expf(s0 - mn);
      float p1 = __expf(s1 - mn);
      float ps = p0 + p1;
      ps += __shfl_xor(ps, 1);
      ps += __shfl_xor(ps, 2);
      ps += __shfl_xor(ps, 4);
      ps += __shfl_xor(ps, 8);
      mrow[r] = mn;
      lrow[r] = lrow[r] * alpha + ps;
      pr0[r] = p0; pr1[r] = p1;
#pragma unroll
      for (int f = 0; f < 8; ++f) accv[f][r] *= alpha;
    }
#pragma unroll
    for (int r = 0; r < 4; ++r) {
      Plds[wave][dg * 4 + r][lr] = (short)bf16_rn(pr0[r]);
      Plds[wave][dg * 4 + r][16 + lr] = (short)bf16_rn(pr1[r]);
    }
    short8 pa = *(const short8*)&Plds[wave][lr][dg * 8];
#pragma unroll
    for (int f = 0; f < 8; ++f) {
      short8 bv = *(const short8*)&VT[s][f * 16 + lr][dg * 8];
      accv[f] = __builtin_amdgcn_mfma_f32_16x16x32_bf16(pa, bv, accv[f], 0, 0, 0);
    }
  }

  // ---- merge wave pairs, write out ----------------------------------------
  __syncthreads();
  float* obuf = (float*)&KH[0][0][0];     // 16 KB, exactly fits
  float* mlbuf = (float*)&Plds[0][0][0];
  if (wk == 1) {
#pragma unroll
    for (int f = 0; f < 8; ++f)
#pragma unroll
      for (int r = 0; r < 4; ++r)
        obuf[(wr * 16 + dg * 4 + r) * 128 + f * 16 + lr] = accv[f][r];
    if (lr == 0) {
#pragma unroll
      for (int r = 0; r < 4; ++r) {
        mlbuf[(wr * 16 + dg * 4 + r) * 2 + 0] = mrow[r];
        mlbuf[(wr * 16 + dg * 4 + r) * 2 + 1] = lrow[r];
      }
    }
  }
  __syncthreads();
  if (wk == 0) {
#pragma unroll
    for (int r = 0; r < 4; ++r) {
      int rowl = wr * 16 + dg * 4 + r;
      float m2 = mlbuf[rowl * 2 + 0], l2 = mlbuf[rowl * 2 + 1];
      float mm = fmaxf(mrow[r], m2);
      float a1 = __expf(mrow[r] - mm), a2 = __expf(m2 - mm);
      float linv = 1.f / (a1 * lrow[r] + a2 * l2);
      int grow = b * NL + q0 + rowl;
#pragma unroll
      for (int f = 0; f < 8; ++f) {
        float o = (a1 * accv[f][r] + a2 * obuf[rowl * 128 + f * 16 + lr]) * linv;
        out[(size_t)grow * ND + f * 16 + lr] = o;
      }
    }
  }
}

extern "C" void kernel_launch(void* const* d_in, const int* in_sizes, int n_in,
                              void* d_out, int out_size, void* d_ws, size_t ws_size,
                              hipStream_t stream) {
  (void)in_sizes; (void)n_in; (void)out_size; (void)ws_size;
  const float* query = (const float*)d_in[0];
  const float* key   = (const float*)d_in[1];
  const float* value = (const float*)d_in[2];
  const float* mask  = (const float*)d_in[3];
  const float* Wq    = (const float*)d_in[4];
  const float* Wk    = (const float*)d_in[5];
  float* out = (float*)d_out;

  char* ws = (char*)d_ws;
  short* wthq = (short*)(ws);                       // 32 KB
  short* wtlq = (short*)(ws + (32 << 10));
  short* wthk = (short*)(ws + (64 << 10));
  short* wtlk = (short*)(ws + (96 << 10));
  unsigned* qhl = (unsigned*)(ws + (128 << 10));    // 8 MB
  short* khp = (short*)(ws + (128 << 10) + (8u << 20));   // 4 MB
  short* klp = (short*)(ws + (128 << 10) + (12u << 20));  // 4 MB
  short* vt  = (short*)(ws + (128 << 10) + (16u << 20));  // 4 MB

  wprep_kernel<<<dim3(32), dim3(256), 0, stream>>>(Wq, Wk, wthq, wtlq, wthk, wtlk);
  vtprep_kernel<<<dim3(512), dim3(256), 0, stream>>>(value, vt);
  proj_kernel<<<dim3(NB * NL / 64, 2), dim3(256), 0, stream>>>(
      query, key, wthq, wtlq, wthk, wtlk, qhl, khp, klp);
  attn_kernel<<<dim3(NB * NL / 32), dim3(256), 0, stream>>>(qhl, khp, klp, vt, mask, out);
}

// Round 6
// 333.670 us; speedup vs baseline: 1.1955x; 1.1955x over previous
//
#include <hip/hip_runtime.h>

#define NB 8
#define NL 2048
#define ND 128
#define NH 128
#define MASKVAL (-1e30f)

typedef __attribute__((ext_vector_type(8))) short short8;
typedef __attribute__((ext_vector_type(4))) float f32x4;

__device__ __forceinline__ unsigned short bf16_rn(float f) {
  unsigned u = __float_as_uint(f);
  u += 0x7fffu + ((u >> 16) & 1u);
  return (unsigned short)(u >> 16);
}
__device__ __forceinline__ float bf16_tof(unsigned short h) {
  return __uint_as_float(((unsigned)h) << 16);
}

// ---------- Kernel 0: W transpose + hi/lo split into bf16 planes ----------
__global__ __launch_bounds__(256) void wprep_kernel(
    const float* __restrict__ Wq, const float* __restrict__ Wk,
    short* __restrict__ wthq, short* __restrict__ wtlq,
    short* __restrict__ wthk, short* __restrict__ wtlk)
{
  int m = blockIdx.x >> 4;            // 0 = q, 1 = k
  int bb = blockIdx.x & 15;
  const float* W = m ? Wk : Wq;
  short* wth = m ? wthk : wthq;
  short* wtl = m ? wtlk : wtlq;
  int idx = bb * 256 + threadIdx.x;   // 0..4095
  int d = idx >> 5, hc = idx & 31;
  float4 wv = *(const float4*)(W + d * NH + hc * 4);
  float vv[4] = {wv.x, wv.y, wv.z, wv.w};
#pragma unroll
  for (int j = 0; j < 4; ++j) {
    int h = hc * 4 + j;
    unsigned short hb = bf16_rn(vv[j]);
    unsigned short lb = bf16_rn(vv[j] - bf16_tof(hb));
    wth[h * ND + d] = (short)hb;
    wtl[h * ND + d] = (short)lb;
  }
}

// ---------- Kernel 1: V transpose to bf16, vt[b][d][key] ------------------
__global__ __launch_bounds__(256) void vtprep_kernel(
    const float* __restrict__ value, short* __restrict__ vt)
{
  __shared__ short Tl[64][66];
  int b = blockIdx.x >> 6;
  int k0 = ((blockIdx.x >> 1) & 31) * 64;
  int d0 = (blockIdx.x & 1) * 64;
  int t = threadIdx.x;
  int dm = t & 7, kp = t >> 3;
  float v0[8], v1[8];
  {
    const float* vp0 = value + (size_t)(b * NL + k0 + kp * 2) * ND + d0 + dm * 8;
    const float* vp1 = vp0 + ND;
    float4 a0 = *(const float4*)vp0;       float4 c0 = *(const float4*)(vp0 + 4);
    float4 a1 = *(const float4*)vp1;       float4 c1 = *(const float4*)(vp1 + 4);
    v0[0]=a0.x; v0[1]=a0.y; v0[2]=a0.z; v0[3]=a0.w; v0[4]=c0.x; v0[5]=c0.y; v0[6]=c0.z; v0[7]=c0.w;
    v1[0]=a1.x; v1[1]=a1.y; v1[2]=a1.z; v1[3]=a1.w; v1[4]=c1.x; v1[5]=c1.y; v1[6]=c1.z; v1[7]=c1.w;
  }
#pragma unroll
  for (int j = 0; j < 8; ++j) {
    unsigned pk = (unsigned)bf16_rn(v0[j]) | ((unsigned)bf16_rn(v1[j]) << 16);
    *(unsigned*)&Tl[dm * 8 + j][kp * 2] = pk;
  }
  __syncthreads();
  int dr = t >> 2, kc = t & 3;
  const unsigned* base = (const unsigned*)&Tl[dr][0];
  unsigned w[8];
#pragma unroll
  for (int i = 0; i < 8; ++i) w[i] = base[kc * 8 + i];
  short* op = vt + (size_t)(b * ND + d0 + dr) * NL + k0 + kc * 16;
  *(uint4*)op = make_uint4(w[0], w[1], w[2], w[3]);
  *(uint4*)(op + 8) = make_uint4(w[4], w[5], w[6], w[7]);
}

// ---------- Kernel 2: projection (split-bf16 MFMA, W from planes) ---------
__global__ __launch_bounds__(256) void proj_kernel(
    const float* __restrict__ query, const float* __restrict__ key,
    const short* __restrict__ wthq, const short* __restrict__ wtlq,
    const short* __restrict__ wthk, const short* __restrict__ wtlk,
    unsigned* __restrict__ qhl, short* __restrict__ khp, short* __restrict__ klp)
{
  const float* X = blockIdx.y ? key : query;
  const short* wth = blockIdx.y ? wthk : wthq;
  const short* wtl = blockIdx.y ? wtlk : wtlq;

  int tid = threadIdx.x;
  int wave = tid >> 6, lane = tid & 63;
  int lr = lane & 15, dg = lane >> 4;
  int arow = blockIdx.x * 64 + wave * 16 + lr;

  short8 ah[4], al[4];
  const float* xr = X + (size_t)arow * ND;
#pragma unroll
  for (int ks = 0; ks < 4; ++ks) {
    float4 a0 = *(const float4*)(xr + ks * 32 + dg * 8);
    float4 a1 = *(const float4*)(xr + ks * 32 + dg * 8 + 4);
    float vv[8] = {a0.x, a0.y, a0.z, a0.w, a1.x, a1.y, a1.z, a1.w};
    short8 h, l;
#pragma unroll
    for (int j = 0; j < 8; ++j) {
      unsigned short hb = bf16_rn(vv[j]);
      h[j] = (short)hb;
      l[j] = (short)bf16_rn(vv[j] - bf16_tof(hb));
    }
    ah[ks] = h; al[ks] = l;
  }

#pragma unroll
  for (int cf = 0; cf < 8; ++cf) {
    f32x4 acc = {0.f, 0.f, 0.f, 0.f};
    int col = cf * 16 + lr;
    const short* whp = wth + (size_t)col * ND;
    const short* wlp = wtl + (size_t)col * ND;
#pragma unroll
    for (int ks = 0; ks < 4; ++ks) {
      short8 wh = *(const short8*)(whp + ks * 32 + dg * 8);
      short8 wl = *(const short8*)(wlp + ks * 32 + dg * 8);
      acc = __builtin_amdgcn_mfma_f32_16x16x32_bf16(ah[ks], wh, acc, 0, 0, 0);
      acc = __builtin_amdgcn_mfma_f32_16x16x32_bf16(al[ks], wh, acc, 0, 0, 0);
      acc = __builtin_amdgcn_mfma_f32_16x16x32_bf16(ah[ks], wl, acc, 0, 0, 0);
    }
#pragma unroll
    for (int r = 0; r < 4; ++r) {
      int orow = blockIdx.x * 64 + wave * 16 + dg * 4 + r;
      float v = acc[r];
      unsigned short hb = bf16_rn(v);
      unsigned short lb = bf16_rn(v - bf16_tof(hb));
      if (blockIdx.y == 0) {
        qhl[(size_t)orow * NH + col] = ((unsigned)lb << 16) | (unsigned)hb;
      } else {
        khp[(size_t)orow * NH + col] = (short)hb;
        klp[(size_t)orow * NH + col] = (short)lb;
      }
    }
  }
}

// ---------- Kernel 3: fused flash attention --------------------------------
// Swizzle convention (both write & read sides, involution):
//   K planes ([32][128] bf16, 16 chunks/row):  phys_ch = ch ^ (row & 7)
//   VT       ([128][32] bf16, 4 chunks/row, chunk idx c = d*4+kc):
//            phys_c = c ^ (d & 7)
__global__ __launch_bounds__(256, 2) void attn_kernel(
    const unsigned* __restrict__ qhl, const short* __restrict__ khp,
    const short* __restrict__ klp, const short* __restrict__ vt,
    const float* __restrict__ mask, float* __restrict__ out)
{
  __shared__ short KH[2][32][128];
  __shared__ short KL[2][32][128];
  __shared__ short VT[2][128 * 32];
  __shared__ short Plds[4][16][32];

  int tid = threadIdx.x;
  int wave = tid >> 6, lane = tid & 63;
  int lr = lane & 15, dg = lane >> 4;
  int b = blockIdx.x & 7, qt = blockIdx.x >> 3;   // XCD swizzle: batch -> XCD
  int wr = wave & 1, wk = wave >> 1;
  int q0 = qt * 32;

  // Q fragments (packed hi|lo u32 -> split)
  short8 qh[4], ql[4];
  {
    const unsigned* qp = qhl + (size_t)(b * NL + q0 + wr * 16 + lr) * NH;
#pragma unroll
    for (int ks = 0; ks < 4; ++ks) {
      uint4 u0 = *(const uint4*)(qp + ks * 32 + dg * 8);
      uint4 u1 = *(const uint4*)(qp + ks * 32 + dg * 8 + 4);
      unsigned uv[8] = {u0.x, u0.y, u0.z, u0.w, u1.x, u1.y, u1.z, u1.w};
      short8 h, l;
#pragma unroll
      for (int j = 0; j < 8; ++j) {
        h[j] = (short)(uv[j] & 0xffffu);
        l[j] = (short)(uv[j] >> 16);
      }
      qh[ks] = h; ql[ks] = l;
    }
  }

  f32x4 accv[8];
#pragma unroll
  for (int f = 0; f < 8; ++f) accv[f] = (f32x4){0.f, 0.f, 0.f, 0.f};
  float mrow[4] = {-__builtin_inff(), -__builtin_inff(), -__builtin_inff(), -__builtin_inff()};
  float lrow[4] = {0.f, 0.f, 0.f, 0.f};

  int su = tid & 127, ss = tid >> 7;
  uint4 rgK[8], rgV[4];

  // prologue stage: pair 0, slot ss handles tile kt = ss
  {
    int kt = ss;
#pragma unroll
    for (int c = 0; c < 4; ++c) {
      int idx = c * 128 + su;
      int row = idx >> 4, ch = idx & 15;
      size_t gk = (size_t)(b * NL + kt * 32 + row) * NH + ch * 8;
      rgK[c]     = *(const uint4*)(khp + gk);
      rgK[4 + c] = *(const uint4*)(klp + gk);
    }
#pragma unroll
    for (int c = 0; c < 4; ++c) {
      int idx = c * 128 + su;
      int d = idx >> 2, kc = idx & 3;
      rgV[c] = *(const uint4*)(vt + (size_t)(b * ND + d) * NL + kt * 32 + kc * 8);
    }
  }

  const int NPAIR = NL / 64;   // 32
  for (int p = 0; p < NPAIR; ++p) {
    __syncthreads();           // previous compute finished reading LDS
    // regs -> LDS with XOR swizzle (2-way banks, free)
#pragma unroll
    for (int c = 0; c < 4; ++c) {
      int idx = c * 128 + su;
      int row = idx >> 4, ch = idx & 15;
      int chp = ch ^ (row & 7);
      *(uint4*)&KH[ss][row][chp * 8] = rgK[c];
      *(uint4*)&KL[ss][row][chp * 8] = rgK[4 + c];
    }
#pragma unroll
    for (int c = 0; c < 4; ++c) {
      int idx = c * 128 + su;
      int cp = idx ^ ((idx >> 2) & 7);
      *(uint4*)&VT[ss][cp * 8] = rgV[c];
    }
    __syncthreads();
    if (p + 1 < NPAIR) {
      int kt = (p + 1) * 2 + ss;
#pragma unroll
      for (int c = 0; c < 4; ++c) {
        int idx = c * 128 + su;
        int row = idx >> 4, ch = idx & 15;
        size_t gk = (size_t)(b * NL + kt * 32 + row) * NH + ch * 8;
        rgK[c]     = *(const uint4*)(khp + gk);
        rgK[4 + c] = *(const uint4*)(klp + gk);
      }
#pragma unroll
      for (int c = 0; c < 4; ++c) {
        int idx = c * 128 + su;
        int d = idx >> 2, kc = idx & 3;
        rgV[c] = *(const uint4*)(vt + (size_t)(b * ND + d) * NL + kt * 32 + kc * 8);
      }
    }

    // ---- compute this wave's tile: kt = p*2 + wk, slot wk
    int kt = p * 2 + wk;
    const int s = wk;
    f32x4 sc0 = {0.f, 0.f, 0.f, 0.f}, sc1 = {0.f, 0.f, 0.f, 0.f};
#pragma unroll
    for (int ks = 0; ks < 4; ++ks) {
      int chp = (ks * 4 + dg) ^ (lr & 7);        // same for row lr and 16+lr
      short8 b0h = *(const short8*)&KH[s][lr][chp * 8];
      short8 b0l = *(const short8*)&KL[s][lr][chp * 8];
      short8 b1h = *(const short8*)&KH[s][16 + lr][chp * 8];
      short8 b1l = *(const short8*)&KL[s][16 + lr][chp * 8];
      sc0 = __builtin_amdgcn_mfma_f32_16x16x32_bf16(qh[ks], b0h, sc0, 0, 0, 0);
      sc1 = __builtin_amdgcn_mfma_f32_16x16x32_bf16(qh[ks], b1h, sc1, 0, 0, 0);
      sc0 = __builtin_amdgcn_mfma_f32_16x16x32_bf16(ql[ks], b0h, sc0, 0, 0, 0);
      sc1 = __builtin_amdgcn_mfma_f32_16x16x32_bf16(ql[ks], b1h, sc1, 0, 0, 0);
      sc0 = __builtin_amdgcn_mfma_f32_16x16x32_bf16(qh[ks], b0l, sc0, 0, 0, 0);
      sc1 = __builtin_amdgcn_mfma_f32_16x16x32_bf16(qh[ks], b1l, sc1, 0, 0, 0);
    }
    float mk0 = mask[b * NL + kt * 32 + lr];
    float mk1 = mask[b * NL + kt * 32 + 16 + lr];
    float pr0[4], pr1[4];
#pragma unroll
    for (int r = 0; r < 4; ++r) {
      float s0 = mk0 * sc0[r] + (1.f - mk0) * MASKVAL;
      float s1 = mk1 * sc1[r] + (1.f - mk1) * MASKVAL;
      float vmax = fmaxf(s0, s1);
      vmax = fmaxf(vmax, __shfl_xor(vmax, 1));
      vmax = fmaxf(vmax, __shfl_xor(vmax, 2));
      vmax = fmaxf(vmax, __shfl_xor(vmax, 4));
      vmax = fmaxf(vmax, __shfl_xor(vmax, 8));
      float mn = fmaxf(mrow[r], vmax);
      float alpha = __expf(mrow[r] - mn);
      float p0 = __expf(s0 - mn);
      float p1 = __expf(s1 - mn);
      float ps = p0 + p1;
      ps += __shfl_xor(ps, 1);
      ps += __shfl_xor(ps, 2);
      ps += __shfl_xor(ps, 4);
      ps += __shfl_xor(ps, 8);
      mrow[r] = mn;
      lrow[r] = lrow[r] * alpha + ps;
      pr0[r] = p0; pr1[r] = p1;
#pragma unroll
      for (int f = 0; f < 8; ++f) accv[f][r] *= alpha;
    }
#pragma unroll
    for (int r = 0; r < 4; ++r) {
      Plds[wave][dg * 4 + r][lr] = (short)bf16_rn(pr0[r]);
      Plds[wave][dg * 4 + r][16 + lr] = (short)bf16_rn(pr1[r]);
    }
    short8 pa = *(const short8*)&Plds[wave][lr][dg * 8];
#pragma unroll
    for (int f = 0; f < 8; ++f) {
      int row = f * 16 + lr;
      int cp = (row * 4 + dg) ^ (row & 7);
      short8 bv = *(const short8*)&VT[s][cp * 8];
      accv[f] = __builtin_amdgcn_mfma_f32_16x16x32_bf16(pa, bv, accv[f], 0, 0, 0);
    }
  }

  // ---- merge wave pairs, write out ----------------------------------------
  __syncthreads();
  float* obuf = (float*)&KH[0][0][0];     // 16 KB, exactly fits
  float* mlbuf = (float*)&Plds[0][0][0];
  if (wk == 1) {
#pragma unroll
    for (int f = 0; f < 8; ++f)
#pragma unroll
      for (int r = 0; r < 4; ++r)
        obuf[(wr * 16 + dg * 4 + r) * 128 + f * 16 + lr] = accv[f][r];
    if (lr == 0) {
#pragma unroll
      for (int r = 0; r < 4; ++r) {
        mlbuf[(wr * 16 + dg * 4 + r) * 2 + 0] = mrow[r];
        mlbuf[(wr * 16 + dg * 4 + r) * 2 + 1] = lrow[r];
      }
    }
  }
  __syncthreads();
  if (wk == 0) {
#pragma unroll
    for (int r = 0; r < 4; ++r) {
      int rowl = wr * 16 + dg * 4 + r;
      float m2 = mlbuf[rowl * 2 + 0], l2 = mlbuf[rowl * 2 + 1];
      float mm = fmaxf(mrow[r], m2);
      float a1 = __expf(mrow[r] - mm), a2 = __expf(m2 - mm);
      float linv = 1.f / (a1 * lrow[r] + a2 * l2);
      int grow = b * NL + q0 + rowl;
#pragma unroll
      for (int f = 0; f < 8; ++f) {
        float o = (a1 * accv[f][r] + a2 * obuf[rowl * 128 + f * 16 + lr]) * linv;
        out[(size_t)grow * ND + f * 16 + lr] = o;
      }
    }
  }
}

extern "C" void kernel_launch(void* const* d_in, const int* in_sizes, int n_in,
                              void* d_out, int out_size, void* d_ws, size_t ws_size,
                              hipStream_t stream) {
  (void)in_sizes; (void)n_in; (void)out_size; (void)ws_size;
  const float* query = (const float*)d_in[0];
  const float* key   = (const float*)d_in[1];
  const float* value = (const float*)d_in[2];
  const float* mask  = (const float*)d_in[3];
  const float* Wq    = (const float*)d_in[4];
  const float* Wk    = (const float*)d_in[5];
  float* out = (float*)d_out;

  char* ws = (char*)d_ws;
  short* wthq = (short*)(ws);                       // 32 KB
  short* wtlq = (short*)(ws + (32 << 10));
  short* wthk = (short*)(ws + (64 << 10));
  short* wtlk = (short*)(ws + (96 << 10));
  unsigned* qhl = (unsigned*)(ws + (128 << 10));    // 8 MB
  short* khp = (short*)(ws + (128 << 10) + (8u << 20));   // 4 MB
  short* klp = (short*)(ws + (128 << 10) + (12u << 20));  // 4 MB
  short* vt  = (short*)(ws + (128 << 10) + (16u << 20));  // 4 MB

  wprep_kernel<<<dim3(32), dim3(256), 0, stream>>>(Wq, Wk, wthq, wtlq, wthk, wtlk);
  vtprep_kernel<<<dim3(512), dim3(256), 0, stream>>>(value, vt);
  proj_kernel<<<dim3(NB * NL / 64, 2), dim3(256), 0, stream>>>(
      query, key, wthq, wtlq, wthk, wtlk, qhl, khp, klp);
  attn_kernel<<<dim3(NB * NL / 32), dim3(256), 0, stream>>>(qhl, khp, klp, vt, mask, out);
}

// Round 7
// 182.967 us; speedup vs baseline: 2.1802x; 1.8237x over previous
//
#include <hip/hip_runtime.h>

#define NB 8
#define NL 2048
#define ND 128
#define NH 128
#define MASKVAL (-1e30f)

typedef __attribute__((ext_vector_type(8))) short short8;
typedef __attribute__((ext_vector_type(4))) float f32x4;

__device__ __forceinline__ unsigned short bf16_rn(float f) {
  unsigned u = __float_as_uint(f);
  u += 0x7fffu + ((u >> 16) & 1u);
  return (unsigned short)(u >> 16);
}
__device__ __forceinline__ float bf16_tof(unsigned short h) {
  return __uint_as_float(((unsigned)h) << 16);
}
// global->LDS DMA: per-lane global src, wave-uniform LDS base (+lane*16 by HW)
__device__ __forceinline__ void gload16(const short* g, short* l) {
  __builtin_amdgcn_global_load_lds(
      (const __attribute__((address_space(1))) unsigned*)g,
      (__attribute__((address_space(3))) unsigned*)l, 16, 0, 0);
}

// kvs tile layout (per (b, kt) of 32 keys): 12288 shorts = 24 KB
//   [0:4096)     K-hi   [row][granule]: short off = row*128 + ((ch ^ (row&7))*8 + (col&7))
//   [4096:8192)  K-lo   same
//   [8192:12288) V^T    granule cp = (d*4+kc) ^ (d&7), 8 keys per granule
// This IS the LDS image; attn stages it with linear gload_lds copies.

// ---------- Kernel 0: W transpose + hi/lo split into bf16 planes ----------
__global__ __launch_bounds__(256) void wprep_kernel(
    const float* __restrict__ Wq, const float* __restrict__ Wk,
    short* __restrict__ wthq, short* __restrict__ wtlq,
    short* __restrict__ wthk, short* __restrict__ wtlk)
{
  int m = blockIdx.x >> 4;            // 0 = q, 1 = k
  int bb = blockIdx.x & 15;
  const float* W = m ? Wk : Wq;
  short* wth = m ? wthk : wthq;
  short* wtl = m ? wtlk : wtlq;
  int idx = bb * 256 + threadIdx.x;   // 0..4095
  int d = idx >> 5, hc = idx & 31;
  float4 wv = *(const float4*)(W + d * NH + hc * 4);
  float vv[4] = {wv.x, wv.y, wv.z, wv.w};
#pragma unroll
  for (int j = 0; j < 4; ++j) {
    int h = hc * 4 + j;
    unsigned short hb = bf16_rn(vv[j]);
    unsigned short lb = bf16_rn(vv[j] - bf16_tof(hb));
    wth[h * ND + d] = (short)hb;
    wtl[h * ND + d] = (short)lb;
  }
}

// ---------- Kernel 1: V transpose -> kvs VT section (pre-swizzled) --------
__global__ __launch_bounds__(256) void vtprep_kernel(
    const float* __restrict__ value, short* __restrict__ kvs)
{
  __shared__ short Tl[64][66];
  int b = blockIdx.x >> 6;
  int k0 = ((blockIdx.x >> 1) & 31) * 64;
  int d0 = (blockIdx.x & 1) * 64;
  int t = threadIdx.x;
  int dm = t & 7, kp = t >> 3;
  float v0[8], v1[8];
  {
    const float* vp0 = value + (size_t)(b * NL + k0 + kp * 2) * ND + d0 + dm * 8;
    const float* vp1 = vp0 + ND;
    float4 a0 = *(const float4*)vp0;       float4 c0 = *(const float4*)(vp0 + 4);
    float4 a1 = *(const float4*)vp1;       float4 c1 = *(const float4*)(vp1 + 4);
    v0[0]=a0.x; v0[1]=a0.y; v0[2]=a0.z; v0[3]=a0.w; v0[4]=c0.x; v0[5]=c0.y; v0[6]=c0.z; v0[7]=c0.w;
    v1[0]=a1.x; v1[1]=a1.y; v1[2]=a1.z; v1[3]=a1.w; v1[4]=c1.x; v1[5]=c1.y; v1[6]=c1.z; v1[7]=c1.w;
  }
#pragma unroll
  for (int j = 0; j < 8; ++j) {
    unsigned pk = (unsigned)bf16_rn(v0[j]) | ((unsigned)bf16_rn(v1[j]) << 16);
    *(unsigned*)&Tl[dm * 8 + j][kp * 2] = pk;
  }
  __syncthreads();
  int dr = t >> 2, kc4 = t & 3;       // dr 0..63; kc4: 16-key chunk
  int d = d0 + dr;
  const unsigned* base = (const unsigned*)&Tl[dr][0];
  unsigned w[8];
#pragma unroll
  for (int i = 0; i < 8; ++i) w[i] = base[kc4 * 8 + i];
  int kt = (k0 >> 5) + (kc4 >> 1);
  int kcg = (kc4 & 1) * 2;
  size_t tbase = (size_t)(b * 64 + kt) * 12288 + 8192;
  int cp0 = (d * 4 + kcg) ^ (d & 7);
  int cp1 = (d * 4 + kcg + 1) ^ (d & 7);
  *(uint4*)(kvs + tbase + cp0 * 8) = make_uint4(w[0], w[1], w[2], w[3]);
  *(uint4*)(kvs + tbase + cp1 * 8) = make_uint4(w[4], w[5], w[6], w[7]);
}

// ---------- Kernel 2: projection (split-bf16 MFMA) ------------------------
// y==0: q -> qhl packed u32. y==1: k -> kvs K-hi/K-lo sections (pre-swizzled).
__global__ __launch_bounds__(256) void proj_kernel(
    const float* __restrict__ query, const float* __restrict__ key,
    const short* __restrict__ wthq, const short* __restrict__ wtlq,
    const short* __restrict__ wthk, const short* __restrict__ wtlk,
    unsigned* __restrict__ qhl, short* __restrict__ kvs)
{
  const float* X = blockIdx.y ? key : query;
  const short* wth = blockIdx.y ? wthk : wthq;
  const short* wtl = blockIdx.y ? wtlk : wtlq;

  int tid = threadIdx.x;
  int wave = tid >> 6, lane = tid & 63;
  int lr = lane & 15, dg = lane >> 4;
  int arow = blockIdx.x * 64 + wave * 16 + lr;

  short8 ah[4], al[4];
  const float* xr = X + (size_t)arow * ND;
#pragma unroll
  for (int ks = 0; ks < 4; ++ks) {
    float4 a0 = *(const float4*)(xr + ks * 32 + dg * 8);
    float4 a1 = *(const float4*)(xr + ks * 32 + dg * 8 + 4);
    float vv[8] = {a0.x, a0.y, a0.z, a0.w, a1.x, a1.y, a1.z, a1.w};
    short8 h, l;
#pragma unroll
    for (int j = 0; j < 8; ++j) {
      unsigned short hb = bf16_rn(vv[j]);
      h[j] = (short)hb;
      l[j] = (short)bf16_rn(vv[j] - bf16_tof(hb));
    }
    ah[ks] = h; al[ks] = l;
  }

#pragma unroll
  for (int cf = 0; cf < 8; ++cf) {
    f32x4 acc = {0.f, 0.f, 0.f, 0.f};
    int col = cf * 16 + lr;
    const short* whp = wth + (size_t)col * ND;
    const short* wlp = wtl + (size_t)col * ND;
#pragma unroll
    for (int ks = 0; ks < 4; ++ks) {
      short8 wh = *(const short8*)(whp + ks * 32 + dg * 8);
      short8 wl = *(const short8*)(wlp + ks * 32 + dg * 8);
      acc = __builtin_amdgcn_mfma_f32_16x16x32_bf16(ah[ks], wh, acc, 0, 0, 0);
      acc = __builtin_amdgcn_mfma_f32_16x16x32_bf16(al[ks], wh, acc, 0, 0, 0);
      acc = __builtin_amdgcn_mfma_f32_16x16x32_bf16(ah[ks], wl, acc, 0, 0, 0);
    }
#pragma unroll
    for (int r = 0; r < 4; ++r) {
      int orow = blockIdx.x * 64 + wave * 16 + dg * 4 + r;
      float v = acc[r];
      unsigned short hb = bf16_rn(v);
      unsigned short lb = bf16_rn(v - bf16_tof(hb));
      if (blockIdx.y == 0) {
        qhl[(size_t)orow * NH + col] = ((unsigned)lb << 16) | (unsigned)hb;
      } else {
        int bb2 = orow >> 11, l2 = orow & (NL - 1);
        int kt = l2 >> 5, krow = l2 & 31;
        size_t tbase = (size_t)(bb2 * 64 + kt) * 12288;
        int gr = krow * 128 + (((col >> 3) ^ (krow & 7)) * 8) + (col & 7);
        kvs[tbase + gr] = (short)hb;
        kvs[tbase + 4096 + gr] = (short)lb;
      }
    }
  }
}

// ---------- Kernel 3: fused flash attention (gload_lds staging) -----------
__global__ __launch_bounds__(256, 3) void attn_kernel(
    const unsigned* __restrict__ qhl, const short* __restrict__ kvs,
    const float* __restrict__ mask, float* __restrict__ out)
{
  __shared__ short KV[2][12288];     // [slot][ Khi | Klo | VT ] = 48 KB
  __shared__ short Plds[4][16][32];  // 4 KB

  int tid = threadIdx.x;
  int wave = tid >> 6, lane = tid & 63;
  int lr = lane & 15, dg = lane >> 4;
  int b = blockIdx.x & 7, qt = blockIdx.x >> 3;   // XCD swizzle: batch -> XCD
  int wr = wave & 1, wk = wave >> 1;
  int q0 = qt * 32;

  // Q fragments (packed hi|lo u32 -> split)
  short8 qh[4], ql[4];
  {
    const unsigned* qp = qhl + (size_t)(b * NL + q0 + wr * 16 + lr) * NH;
#pragma unroll
    for (int ks = 0; ks < 4; ++ks) {
      uint4 u0 = *(const uint4*)(qp + ks * 32 + dg * 8);
      uint4 u1 = *(const uint4*)(qp + ks * 32 + dg * 8 + 4);
      unsigned uv[8] = {u0.x, u0.y, u0.z, u0.w, u1.x, u1.y, u1.z, u1.w};
      short8 h, l;
#pragma unroll
      for (int j = 0; j < 8; ++j) {
        h[j] = (short)(uv[j] & 0xffffu);
        l[j] = (short)(uv[j] >> 16);
      }
      qh[ks] = h; ql[ks] = l;
    }
  }

  f32x4 accv[8];
#pragma unroll
  for (int f = 0; f < 8; ++f) accv[f] = (f32x4){0.f, 0.f, 0.f, 0.f};
  float mrow[4] = {-__builtin_inff(), -__builtin_inff(), -__builtin_inff(), -__builtin_inff()};
  float lrow[4] = {0.f, 0.f, 0.f, 0.f};

  // staging plan: 48 KB per pair = 48 1-KB wave-copies; wave w does 12:
  //   slot = wk, short-offset base = wr*6144
  const short* gb = kvs + (size_t)(b * 64) * 12288;
  int offbase = wr * 6144;
  const short* Kbase = &KV[wk][0];

  for (int p = 0; p < 32; ++p) {
    __syncthreads();               // pair p-1 fully consumed
    {
      const short* gt = gb + (size_t)(p * 2 + wk) * 12288 + offbase + lane * 8;
      short* lt = &KV[wk][offbase];
#pragma unroll
      for (int i = 0; i < 12; ++i)
        gload16(gt + i * 512, lt + i * 512);
    }
    asm volatile("s_waitcnt vmcnt(0)" ::: "memory");
    __syncthreads();               // all waves' DMA visible

    int kt = p * 2 + wk;
    f32x4 sc0 = {0.f, 0.f, 0.f, 0.f}, sc1 = {0.f, 0.f, 0.f, 0.f};
#pragma unroll
    for (int ks = 0; ks < 4; ++ks) {
      int chp = (((ks * 4 + dg) ^ (lr & 7)) * 8);
      short8 b0h = *(const short8*)(Kbase + lr * 128 + chp);
      short8 b0l = *(const short8*)(Kbase + 4096 + lr * 128 + chp);
      short8 b1h = *(const short8*)(Kbase + (16 + lr) * 128 + chp);
      short8 b1l = *(const short8*)(Kbase + 4096 + (16 + lr) * 128 + chp);
      sc0 = __builtin_amdgcn_mfma_f32_16x16x32_bf16(qh[ks], b0h, sc0, 0, 0, 0);
      sc1 = __builtin_amdgcn_mfma_f32_16x16x32_bf16(qh[ks], b1h, sc1, 0, 0, 0);
      sc0 = __builtin_amdgcn_mfma_f32_16x16x32_bf16(ql[ks], b0h, sc0, 0, 0, 0);
      sc1 = __builtin_amdgcn_mfma_f32_16x16x32_bf16(ql[ks], b1h, sc1, 0, 0, 0);
      sc0 = __builtin_amdgcn_mfma_f32_16x16x32_bf16(qh[ks], b0l, sc0, 0, 0, 0);
      sc1 = __builtin_amdgcn_mfma_f32_16x16x32_bf16(qh[ks], b1l, sc1, 0, 0, 0);
    }
    float mk0 = mask[b * NL + kt * 32 + lr];
    float mk1 = mask[b * NL + kt * 32 + 16 + lr];
    float pr0[4], pr1[4];
#pragma unroll
    for (int r = 0; r < 4; ++r) {
      float s0 = mk0 * sc0[r] + (1.f - mk0) * MASKVAL;
      float s1 = mk1 * sc1[r] + (1.f - mk1) * MASKVAL;
      float vmax = fmaxf(s0, s1);
      vmax = fmaxf(vmax, __shfl_xor(vmax, 1));
      vmax = fmaxf(vmax, __shfl_xor(vmax, 2));
      vmax = fmaxf(vmax, __shfl_xor(vmax, 4));
      vmax = fmaxf(vmax, __shfl_xor(vmax, 8));
      float mn = fmaxf(mrow[r], vmax);
      float alpha = __expf(mrow[r] - mn);
      float p0 = __expf(s0 - mn);
      float p1 = __expf(s1 - mn);
      float ps = p0 + p1;
      ps += __shfl_xor(ps, 1);
      ps += __shfl_xor(ps, 2);
      ps += __shfl_xor(ps, 4);
      ps += __shfl_xor(ps, 8);
      mrow[r] = mn;
      lrow[r] = lrow[r] * alpha + ps;
      pr0[r] = p0; pr1[r] = p1;
#pragma unroll
      for (int f = 0; f < 8; ++f) accv[f][r] *= alpha;
    }
#pragma unroll
    for (int r = 0; r < 4; ++r) {
      Plds[wave][dg * 4 + r][lr] = (short)bf16_rn(pr0[r]);
      Plds[wave][dg * 4 + r][16 + lr] = (short)bf16_rn(pr1[r]);
    }
    short8 pa = *(const short8*)&Plds[wave][lr][dg * 8];
#pragma unroll
    for (int f = 0; f < 8; ++f) {
      int row = f * 16 + lr;
      int cp = (((row * 4 + dg) ^ (row & 7)) * 8);
      short8 bv = *(const short8*)(Kbase + 8192 + cp);
      accv[f] = __builtin_amdgcn_mfma_f32_16x16x32_bf16(pa, bv, accv[f], 0, 0, 0);
    }
  }

  // ---- merge wave pairs, write out ----------------------------------------
  __syncthreads();
  float* obuf = (float*)&KV[0][0];       // 16 KB scratch
  float* mlbuf = (float*)&Plds[0][0][0];
  if (wk == 1) {
#pragma unroll
    for (int f = 0; f < 8; ++f)
#pragma unroll
      for (int r = 0; r < 4; ++r)
        obuf[(wr * 16 + dg * 4 + r) * 128 + f * 16 + lr] = accv[f][r];
    if (lr == 0) {
#pragma unroll
      for (int r = 0; r < 4; ++r) {
        mlbuf[(wr * 16 + dg * 4 + r) * 2 + 0] = mrow[r];
        mlbuf[(wr * 16 + dg * 4 + r) * 2 + 1] = lrow[r];
      }
    }
  }
  __syncthreads();
  if (wk == 0) {
#pragma unroll
    for (int r = 0; r < 4; ++r) {
      int rowl = wr * 16 + dg * 4 + r;
      float m2 = mlbuf[rowl * 2 + 0], l2 = mlbuf[rowl * 2 + 1];
      float mm = fmaxf(mrow[r], m2);
      float a1 = __expf(mrow[r] - mm), a2 = __expf(m2 - mm);
      float linv = 1.f / (a1 * lrow[r] + a2 * l2);
      int grow = b * NL + q0 + rowl;
#pragma unroll
      for (int f = 0; f < 8; ++f) {
        float o = (a1 * accv[f][r] + a2 * obuf[rowl * 128 + f * 16 + lr]) * linv;
        out[(size_t)grow * ND + f * 16 + lr] = o;
      }
    }
  }
}

extern "C" void kernel_launch(void* const* d_in, const int* in_sizes, int n_in,
                              void* d_out, int out_size, void* d_ws, size_t ws_size,
                              hipStream_t stream) {
  (void)in_sizes; (void)n_in; (void)out_size; (void)ws_size;
  const float* query = (const float*)d_in[0];
  const float* key   = (const float*)d_in[1];
  const float* value = (const float*)d_in[2];
  const float* mask  = (const float*)d_in[3];
  const float* Wq    = (const float*)d_in[4];
  const float* Wk    = (const float*)d_in[5];
  float* out = (float*)d_out;

  char* ws = (char*)d_ws;
  short* wthq = (short*)(ws);                       // 4 x 32 KB
  short* wtlq = (short*)(ws + (32 << 10));
  short* wthk = (short*)(ws + (64 << 10));
  short* wtlk = (short*)(ws + (96 << 10));
  unsigned* qhl = (unsigned*)(ws + (128 << 10));    // 8 MB
  short* kvs = (short*)(ws + (128 << 10) + (8u << 20));   // 12 MB tiled K/V

  wprep_kernel<<<dim3(32), dim3(256), 0, stream>>>(Wq, Wk, wthq, wtlq, wthk, wtlk);
  vtprep_kernel<<<dim3(512), dim3(256), 0, stream>>>(value, kvs);
  proj_kernel<<<dim3(NB * NL / 64, 2), dim3(256), 0, stream>>>(
      query, key, wthq, wtlq, wthk, wtlk, qhl, kvs);
  attn_kernel<<<dim3(NB * NL / 32), dim3(256), 0, stream>>>(qhl, kvs, mask, out);
}